// Round 3
// baseline (1180.396 us; speedup 1.0000x reference)
//
#include <hip/hip_runtime.h>
#include <math.h>

#define N_NODES 100000
#define N_EDGES 3200000
#define IN_DIM  64
#define HID     16
#define OUTD    2

// workspace layout (float offsets) — total 14.8 MB
#define OFF_DINV 0
#define OFF_H1   100352                      // pad N to multiple of 256
#define OFF_AGG1 (OFF_H1 + N_NODES * HID)
#define OFF_H2   (OFF_AGG1 + N_NODES * HID)
#define OFF_AGG2 (OFF_H2 + N_NODES * OUTD)
#define WS_FLOATS (OFF_AGG2 + N_NODES * OUTD)

__global__ void k_degree(const int* __restrict__ dst, int* __restrict__ cnt) {
    int e = blockIdx.x * blockDim.x + threadIdx.x;
    if (e < N_EDGES) atomicAdd(&cnt[dst[e]], 1);
}

__global__ void k_dinv(float* __restrict__ dinv) {
    int n = blockIdx.x * blockDim.x + threadIdx.x;
    if (n < N_NODES) {
        int c = ((const int*)dinv)[n];           // in-place: counts -> rsqrt(deg)
        dinv[n] = rsqrtf((float)(c + 1));        // +1 for self-loop
    }
}

__global__ void k_lin1(const float* __restrict__ x, const float* __restrict__ W1,
                       float* __restrict__ h1) {
    __shared__ float w[IN_DIM * HID];
    for (int i = threadIdx.x; i < IN_DIM * HID; i += blockDim.x) w[i] = W1[i];
    __syncthreads();
    int n = blockIdx.x * blockDim.x + threadIdx.x;
    if (n >= N_NODES) return;
    float acc[HID];
#pragma unroll
    for (int j = 0; j < HID; j++) acc[j] = 0.f;
    const float4* xr = (const float4*)(x + (size_t)n * IN_DIM);
#pragma unroll
    for (int k4 = 0; k4 < IN_DIM / 4; k4++) {
        float4 v = xr[k4];
#pragma unroll
        for (int j = 0; j < HID; j++) {
            acc[j] += v.x * w[(k4 * 4 + 0) * HID + j]
                    + v.y * w[(k4 * 4 + 1) * HID + j]
                    + v.z * w[(k4 * 4 + 2) * HID + j]
                    + v.w * w[(k4 * 4 + 3) * HID + j];
        }
    }
    float4* o = (float4*)(h1 + (size_t)n * HID);
    o[0] = make_float4(acc[0], acc[1], acc[2], acc[3]);
    o[1] = make_float4(acc[4], acc[5], acc[6], acc[7]);
    o[2] = make_float4(acc[8], acc[9], acc[10], acc[11]);
    o[3] = make_float4(acc[12], acc[13], acc[14], acc[15]);
}

// 4 threads per edge; each handles one float4 slice of the 16-wide message
__global__ void k_scatter1(const int* __restrict__ src, const int* __restrict__ dst,
                           const float* __restrict__ dinv, const float* __restrict__ h1,
                           float* __restrict__ agg1) {
    int gid = blockIdx.x * blockDim.x + threadIdx.x;
    int e = gid >> 2;
    int q = gid & 3;
    if (e >= N_EDGES) return;
    int s = src[e], d = dst[e];
    float w = dinv[s];
    float4 v = *(const float4*)(h1 + (size_t)s * HID + q * 4);
    float* a = agg1 + (size_t)d * HID + q * 4;
    atomicAdd(a + 0, w * v.x);
    atomicAdd(a + 1, w * v.y);
    atomicAdd(a + 2, w * v.z);
    atomicAdd(a + 3, w * v.w);
}

// finalize layer1 (+bias, relu) fused with tiny matmul @W2
__global__ void k_fin1(const float* __restrict__ dinv, const float* __restrict__ h1,
                       const float* __restrict__ agg1, const float* __restrict__ b1,
                       const float* __restrict__ W2, float* __restrict__ h2) {
    int n = blockIdx.x * blockDim.x + threadIdx.x;
    if (n >= N_NODES) return;
    float di = dinv[n], di2 = di * di;
    float o0 = 0.f, o1 = 0.f;
    const float4* ar = (const float4*)(agg1 + (size_t)n * HID);
    const float4* hr = (const float4*)(h1 + (size_t)n * HID);
#pragma unroll
    for (int j4 = 0; j4 < HID / 4; j4++) {
        float4 a = ar[j4], h = hr[j4];
        float vv[4] = { a.x * di + h.x * di2, a.y * di + h.y * di2,
                        a.z * di + h.z * di2, a.w * di + h.w * di2 };
#pragma unroll
        for (int t = 0; t < 4; t++) {
            int j = j4 * 4 + t;
            float v = fmaxf(vv[t] + b1[j], 0.f);
            o0 += v * W2[j * 2 + 0];
            o1 += v * W2[j * 2 + 1];
        }
    }
    h2[(size_t)n * 2 + 0] = o0;
    h2[(size_t)n * 2 + 1] = o1;
}

__global__ void k_scatter2(const int* __restrict__ src, const int* __restrict__ dst,
                           const float* __restrict__ dinv, const float* __restrict__ h2,
                           float* __restrict__ agg2) {
    int e = blockIdx.x * blockDim.x + threadIdx.x;
    if (e >= N_EDGES) return;
    int s = src[e], d = dst[e];
    float w = dinv[s];
    float2 v = *(const float2*)(h2 + (size_t)s * 2);
    atomicAdd(&agg2[(size_t)d * 2 + 0], w * v.x);
    atomicAdd(&agg2[(size_t)d * 2 + 1], w * v.y);
}

__global__ void k_fin2(const float* __restrict__ dinv, const float* __restrict__ h2,
                       const float* __restrict__ agg2, const float* __restrict__ b2,
                       float* __restrict__ out) {
    int n = blockIdx.x * blockDim.x + threadIdx.x;
    if (n >= N_NODES) return;
    float di = dinv[n], di2 = di * di;
    float2 a = *(const float2*)(agg2 + (size_t)n * 2);
    float2 h = *(const float2*)(h2 + (size_t)n * 2);
    float o0 = a.x * di + h.x * di2 + b2[0];
    float o1 = a.y * di + h.y * di2 + b2[1];
    float m = fmaxf(o0, o1);
    float lse = m + logf(expf(o0 - m) + expf(o1 - m));
    ((float2*)out)[n] = make_float2(o0 - lse, o1 - lse);
}

extern "C" void kernel_launch(void* const* d_in, const int* in_sizes, int n_in,
                              void* d_out, int out_size, void* d_ws, size_t ws_size,
                              hipStream_t stream) {
    const float* x  = (const float*)d_in[0];
    const int*   ei = (const int*)d_in[1];
    const int*   srcv = ei;
    const int*   dstv = ei + N_EDGES;
    const float* W1 = (const float*)d_in[2];
    const float* b1 = (const float*)d_in[3];
    const float* W2 = (const float*)d_in[4];
    const float* b2 = (const float*)d_in[5];
    float* out = (float*)d_out;

    float* ws   = (float*)d_ws;
    float* dinv = ws + OFF_DINV;
    float* h1   = ws + OFF_H1;
    float* agg1 = ws + OFF_AGG1;
    float* h2   = ws + OFF_H2;
    float* agg2 = ws + OFF_AGG2;

    hipMemsetAsync(d_ws, 0, (size_t)WS_FLOATS * sizeof(float), stream);

    k_degree<<<(N_EDGES + 255) / 256, 256, 0, stream>>>(dstv, (int*)dinv);
    k_dinv<<<(N_NODES + 255) / 256, 256, 0, stream>>>(dinv);
    k_lin1<<<(N_NODES + 255) / 256, 256, 0, stream>>>(x, W1, h1);
    k_scatter1<<<(4 * N_EDGES + 255) / 256, 256, 0, stream>>>(srcv, dstv, dinv, h1, agg1);
    k_fin1<<<(N_NODES + 255) / 256, 256, 0, stream>>>(dinv, h1, agg1, b1, W2, h2);
    k_scatter2<<<(N_EDGES + 255) / 256, 256, 0, stream>>>(srcv, dstv, dinv, h2, agg2);
    k_fin2<<<(N_NODES + 255) / 256, 256, 0, stream>>>(dinv, h2, agg2, b2, out);
}

// Round 5
// 604.255 us; speedup vs baseline: 1.9535x; 1.9535x over previous
//
#include <hip/hip_runtime.h>
#include <math.h>

#define N_NODES 100000
#define N_EDGES 3200000
#define IN_DIM  64
#define HID     16
#define OUTD    2

#define NPAD    100352            // N padded to multiple of 1024
#define CHUNK   1024
#define NBLK    (NPAD / CHUNK)    // 98 scan blocks

// workspace layout (float/int offsets) — ~21.2 MB total
#define OFF_CNT   0                          // int counts -> float dinv (in place)
#define OFF_RS    (OFF_CNT + NPAD)           // row starts (exclusive scan)
#define OFF_CUR   (OFF_RS + NPAD)            // fill cursors -> row ends after fill
#define OFF_PART  (OFF_CUR + NPAD)           // per-block partial sums (NBLK <= 1024)
#define OFF_H1    (OFF_PART + 1024)          // h1s = dinv[n] * (x@W1)   [N,16]
#define OFF_H2    (OFF_H1 + N_NODES * HID)   // h2s = dinv[n] * h2_raw   [N,2]
#define OFF_CSR   (OFF_H2 + N_NODES * OUTD)  // CSR src ids (int)        [E]
#define WS_FLOATS (OFF_CSR + N_EDGES)

__global__ void k_degree(const int* __restrict__ dst, int* __restrict__ cnt) {
    int e = blockIdx.x * blockDim.x + threadIdx.x;
    if (e < N_EDGES) atomicAdd(&cnt[dst[e]], 1);
}

// per-block sums of cnt (chunk=1024, 256 thr x int4)
__global__ void k_scanA(const int* __restrict__ cnt, int* __restrict__ part) {
    int t = threadIdx.x;
    int base = blockIdx.x * CHUNK + t * 4;
    int4 c = *(const int4*)(cnt + base);
    int s = c.x + c.y + c.z + c.w;
#pragma unroll
    for (int off = 32; off; off >>= 1) s += __shfl_down(s, off, 64);
    __shared__ int wsum[4];
    if ((t & 63) == 0) wsum[t >> 6] = s;
    __syncthreads();
    if (t == 0) part[blockIdx.x] = wsum[0] + wsum[1] + wsum[2] + wsum[3];
}

// exclusive scan of the NBLK partials, in place (1 block, 128 thr)
__global__ void k_scanB(int* __restrict__ part) {
    int i = threadIdx.x;
    int lane = i & 63;
    int v = (i < NBLK) ? part[i] : 0;
    int x = v;
#pragma unroll
    for (int off = 1; off < 64; off <<= 1) {
        int y = __shfl_up(x, off, 64);
        if (lane >= off) x += y;
    }
    __shared__ int w0;
    if (i == 63) w0 = x;
    __syncthreads();
    if (i >= 64) x += w0;
    if (i < NBLK) part[i] = x - v;   // exclusive
}

// write row starts + cursors; convert cnt -> dinv in place
__global__ void k_scanC(int* __restrict__ cnt_dinv, const int* __restrict__ part,
                        int* __restrict__ rs, int* __restrict__ cur) {
    int t = threadIdx.x;
    int lane = t & 63, wid = t >> 6;
    int base = blockIdx.x * CHUNK + t * 4;
    int4 c = *(const int4*)(cnt_dinv + base);
    int s0 = c.x, s1 = s0 + c.y, s2 = s1 + c.z, tot = s2 + c.w;
    int x = tot;
#pragma unroll
    for (int off = 1; off < 64; off <<= 1) {
        int y = __shfl_up(x, off, 64);
        if (lane >= off) x += y;
    }
    int texcl = x - tot;
    __shared__ int wtot[4];
    if (lane == 63) wtot[wid] = x;
    __syncthreads();
    int wbase = 0;
#pragma unroll
    for (int w = 0; w < 4; w++) if (w < wid) wbase += wtot[w];
    int b = part[blockIdx.x] + wbase + texcl;
    int4 r = make_int4(b, b + s0, b + s1, b + s2);
    *(int4*)(rs + base) = r;
    *(int4*)(cur + base) = r;
    float4 dv = make_float4(rsqrtf((float)(c.x + 1)), rsqrtf((float)(c.y + 1)),
                            rsqrtf((float)(c.z + 1)), rsqrtf((float)(c.w + 1)));
    *(float4*)((float*)cnt_dinv + base) = dv;
}

// bucket src ids into CSR (one int atomic per edge)
__global__ void k_fill(const int* __restrict__ src, const int* __restrict__ dst,
                       int* __restrict__ cur, int* __restrict__ csr) {
    int e = blockIdx.x * blockDim.x + threadIdx.x;
    if (e >= N_EDGES) return;
    int s = src[e], d = dst[e];
    int pos = atomicAdd(&cur[d], 1);
    csr[pos] = s;
}

// h1s[n] = dinv[n] * (x[n] @ W1)
__global__ void k_lin1s(const float* __restrict__ x, const float* __restrict__ W1,
                        const float* __restrict__ dinv, float* __restrict__ h1s) {
    __shared__ float w[IN_DIM * HID];
    for (int i = threadIdx.x; i < IN_DIM * HID; i += blockDim.x) w[i] = W1[i];
    __syncthreads();
    int n = blockIdx.x * blockDim.x + threadIdx.x;
    if (n >= N_NODES) return;
    float acc[HID];
#pragma unroll
    for (int j = 0; j < HID; j++) acc[j] = 0.f;
    const float4* xr = (const float4*)(x + (size_t)n * IN_DIM);
#pragma unroll
    for (int k4 = 0; k4 < IN_DIM / 4; k4++) {
        float4 v = xr[k4];
#pragma unroll
        for (int j = 0; j < HID; j++) {
            acc[j] += v.x * w[(k4 * 4 + 0) * HID + j]
                    + v.y * w[(k4 * 4 + 1) * HID + j]
                    + v.z * w[(k4 * 4 + 2) * HID + j]
                    + v.w * w[(k4 * 4 + 3) * HID + j];
        }
    }
    float di = dinv[n];
    float4* o = (float4*)(h1s + (size_t)n * HID);
    o[0] = make_float4(di * acc[0], di * acc[1], di * acc[2], di * acc[3]);
    o[1] = make_float4(di * acc[4], di * acc[5], di * acc[6], di * acc[7]);
    o[2] = make_float4(di * acc[8], di * acc[9], di * acc[10], di * acc[11]);
    o[3] = make_float4(di * acc[12], di * acc[13], di * acc[14], di * acc[15]);
}

// pull layer 1, fused bias+relu+@W2: one wave per node, lanes=[4 edges x 16 feats]
__global__ __launch_bounds__(256) void k_pull1(
    const int* __restrict__ rs, const int* __restrict__ re,
    const int* __restrict__ csr, const float* __restrict__ h1s,
    const float* __restrict__ dinv, const float* __restrict__ b1,
    const float* __restrict__ W2, float* __restrict__ h2s) {
    int n = blockIdx.x * 4 + (threadIdx.x >> 6);
    if (n >= N_NODES) return;
    int lane = threadIdx.x & 63;
    int es = lane >> 4, j = lane & 15;
    int beg = rs[n], end = re[n];
    float acc = 0.f;
    for (int i = beg + es; i < end; i += 4) {
        int s = csr[i];
        acc += h1s[(size_t)s * HID + j];
    }
    acc += __shfl_xor(acc, 16, 64);
    acc += __shfl_xor(acc, 32, 64);
    float di = dinv[n];
    float v = fmaxf(di * (acc + h1s[(size_t)n * HID + j]) + b1[j], 0.f);
    float p0 = v * W2[j * 2 + 0];
    float p1 = v * W2[j * 2 + 1];
#pragma unroll
    for (int m = 1; m <= 8; m <<= 1) {
        p0 += __shfl_xor(p0, m, 64);
        p1 += __shfl_xor(p1, m, 64);
    }
    if (lane == 0) *(float2*)(h2s + (size_t)n * 2) = make_float2(di * p0, di * p1);
}

// pull layer 2, fused log_softmax: one wave per node, lanes=[32 edges x 2 feats]
__global__ __launch_bounds__(256) void k_pull2(
    const int* __restrict__ rs, const int* __restrict__ re,
    const int* __restrict__ csr, const float* __restrict__ h2s,
    const float* __restrict__ dinv, const float* __restrict__ b2,
    float* __restrict__ out) {
    int n = blockIdx.x * 4 + (threadIdx.x >> 6);
    if (n >= N_NODES) return;
    int lane = threadIdx.x & 63;
    int e = lane >> 1, k = lane & 1;
    int beg = rs[n], end = re[n];
    float acc = 0.f;
    for (int i = beg + e; i < end; i += 32) {
        int s = csr[i];
        acc += h2s[(size_t)s * 2 + k];
    }
#pragma unroll
    for (int m = 2; m <= 32; m <<= 1) acc += __shfl_xor(acc, m, 64);
    float di = dinv[n];
    float o = di * (acc + h2s[(size_t)n * 2 + k]) + b2[k];
    float other = __shfl_xor(o, 1, 64);
    float mx = fmaxf(o, other);
    float lse = mx + logf(expf(o - mx) + expf(other - mx));
    if (lane < 2) out[(size_t)n * 2 + k] = o - lse;
}

extern "C" void kernel_launch(void* const* d_in, const int* in_sizes, int n_in,
                              void* d_out, int out_size, void* d_ws, size_t ws_size,
                              hipStream_t stream) {
    const float* x  = (const float*)d_in[0];
    const int*   ei = (const int*)d_in[1];
    const int*   srcv = ei;
    const int*   dstv = ei + N_EDGES;
    const float* W1 = (const float*)d_in[2];
    const float* b1 = (const float*)d_in[3];
    const float* W2 = (const float*)d_in[4];
    const float* b2 = (const float*)d_in[5];
    float* out = (float*)d_out;

    float* ws   = (float*)d_ws;
    int*   cnt  = (int*)(ws + OFF_CNT);      // becomes dinv (float) after scanC
    float* dinv = ws + OFF_CNT;
    int*   rs   = (int*)(ws + OFF_RS);
    int*   cur  = (int*)(ws + OFF_CUR);      // becomes row-end after fill
    int*   part = (int*)(ws + OFF_PART);
    float* h1s  = ws + OFF_H1;
    float* h2s  = ws + OFF_H2;
    int*   csr  = (int*)(ws + OFF_CSR);

    hipMemsetAsync(cnt, 0, (size_t)NPAD * sizeof(int), stream);

    k_degree<<<(N_EDGES + 255) / 256, 256, 0, stream>>>(dstv, cnt);
    k_scanA<<<NBLK, 256, 0, stream>>>(cnt, part);
    k_scanB<<<1, 128, 0, stream>>>(part);
    k_scanC<<<NBLK, 256, 0, stream>>>(cnt, part, rs, cur);
    k_fill<<<(N_EDGES + 255) / 256, 256, 0, stream>>>(srcv, dstv, cur, csr);
    k_lin1s<<<(N_NODES + 255) / 256, 256, 0, stream>>>(x, W1, dinv, h1s);
    k_pull1<<<(N_NODES + 3) / 4, 256, 0, stream>>>(rs, cur, csr, h1s, dinv, b1, W2, h2s);
    k_pull2<<<(N_NODES + 3) / 4, 256, 0, stream>>>(rs, cur, csr, h2s, dinv, b2, out);
}

// Round 6
// 546.543 us; speedup vs baseline: 2.1597x; 1.1056x over previous
//
#include <hip/hip_runtime.h>
#include <math.h>

#define N_NODES 100000
#define N_EDGES 3200000
#define IN_DIM  64
#define HID     16
#define OUTD    2

#define NPAD    100352            // N padded to multiple of 1024
#define CHUNK   1024
#define NBLK    (NPAD / CHUNK)    // 98 scan blocks

#define NPASS   8
#define PASS_SZ (N_NODES / NPASS) // 12500 exactly

// workspace layout (float/int offsets) — ~21.2 MB total
#define OFF_CNT   0                          // int counts -> float dinv (in place)
#define OFF_RS    (OFF_CNT + NPAD)           // row starts (exclusive scan)
#define OFF_CUR   (OFF_RS + NPAD)            // fill cursors -> row ends after fill
#define OFF_PART  (OFF_CUR + NPAD)           // per-block partial sums (NBLK <= 1024)
#define OFF_H1    (OFF_PART + 1024)          // h1s = dinv[n] * (x@W1)   [N,16]
#define OFF_H2    (OFF_H1 + N_NODES * HID)   // h2s = dinv[n] * h2_raw   [N,2]
#define OFF_CSR   (OFF_H2 + N_NODES * OUTD)  // CSR src ids (int)        [E]
#define WS_FLOATS (OFF_CSR + N_EDGES)

__global__ void k_degree(const int* __restrict__ dst, int* __restrict__ cnt) {
    int e = blockIdx.x * blockDim.x + threadIdx.x;
    if (e < N_EDGES) atomicAdd(&cnt[dst[e]], 1);
}

// per-block sums of cnt (chunk=1024, 256 thr x int4)
__global__ void k_scanA(const int* __restrict__ cnt, int* __restrict__ part) {
    int t = threadIdx.x;
    int base = blockIdx.x * CHUNK + t * 4;
    int4 c = *(const int4*)(cnt + base);
    int s = c.x + c.y + c.z + c.w;
#pragma unroll
    for (int off = 32; off; off >>= 1) s += __shfl_down(s, off, 64);
    __shared__ int wsum[4];
    if ((t & 63) == 0) wsum[t >> 6] = s;
    __syncthreads();
    if (t == 0) part[blockIdx.x] = wsum[0] + wsum[1] + wsum[2] + wsum[3];
}

// exclusive scan of the NBLK partials, in place (1 block, 128 thr)
__global__ void k_scanB(int* __restrict__ part) {
    int i = threadIdx.x;
    int lane = i & 63;
    int v = (i < NBLK) ? part[i] : 0;
    int x = v;
#pragma unroll
    for (int off = 1; off < 64; off <<= 1) {
        int y = __shfl_up(x, off, 64);
        if (lane >= off) x += y;
    }
    __shared__ int w0;
    if (i == 63) w0 = x;
    __syncthreads();
    if (i >= 64) x += w0;
    if (i < NBLK) part[i] = x - v;   // exclusive
}

// write row starts + cursors; convert cnt -> dinv in place
__global__ void k_scanC(int* __restrict__ cnt_dinv, const int* __restrict__ part,
                        int* __restrict__ rs, int* __restrict__ cur) {
    int t = threadIdx.x;
    int lane = t & 63, wid = t >> 6;
    int base = blockIdx.x * CHUNK + t * 4;
    int4 c = *(const int4*)(cnt_dinv + base);
    int s0 = c.x, s1 = s0 + c.y, s2 = s1 + c.z, tot = s2 + c.w;
    int x = tot;
#pragma unroll
    for (int off = 1; off < 64; off <<= 1) {
        int y = __shfl_up(x, off, 64);
        if (lane >= off) x += y;
    }
    int texcl = x - tot;
    __shared__ int wtot[4];
    if (lane == 63) wtot[wid] = x;
    __syncthreads();
    int wbase = 0;
#pragma unroll
    for (int w = 0; w < 4; w++) if (w < wid) wbase += wtot[w];
    int b = part[blockIdx.x] + wbase + texcl;
    int4 r = make_int4(b, b + s0, b + s1, b + s2);
    *(int4*)(rs + base) = r;
    *(int4*)(cur + base) = r;
    float4 dv = make_float4(rsqrtf((float)(c.x + 1)), rsqrtf((float)(c.y + 1)),
                            rsqrtf((float)(c.z + 1)), rsqrtf((float)(c.w + 1)));
    *(float4*)((float*)cnt_dinv + base) = dv;
}

// dst-range-partitioned CSR fill: pass handles dst in [lo,hi) only, so the
// dirty csr region (~1.6 MB) stays L2-resident and stores coalesce into
// mostly-full lines before write-back. 4 edges per thread (int4 dst read).
__global__ __launch_bounds__(256) void k_fillpass(
    const int* __restrict__ src, const int* __restrict__ dst,
    int* __restrict__ cur, int* __restrict__ csr, int lo, int hi) {
    int base = (blockIdx.x * 256 + threadIdx.x) * 4;
    if (base >= N_EDGES) return;
    int4 d4 = *(const int4*)(dst + base);
#pragma unroll
    for (int i = 0; i < 4; i++) {
        int d = (&d4.x)[i];
        if (d >= lo && d < hi) {
            int pos = atomicAdd(&cur[d], 1);
            csr[pos] = src[base + i];
        }
    }
}

// h1s[n] = dinv[n] * (x[n] @ W1)
__global__ void k_lin1s(const float* __restrict__ x, const float* __restrict__ W1,
                        const float* __restrict__ dinv, float* __restrict__ h1s) {
    __shared__ float w[IN_DIM * HID];
    for (int i = threadIdx.x; i < IN_DIM * HID; i += blockDim.x) w[i] = W1[i];
    __syncthreads();
    int n = blockIdx.x * blockDim.x + threadIdx.x;
    if (n >= N_NODES) return;
    float acc[HID];
#pragma unroll
    for (int j = 0; j < HID; j++) acc[j] = 0.f;
    const float4* xr = (const float4*)(x + (size_t)n * IN_DIM);
#pragma unroll
    for (int k4 = 0; k4 < IN_DIM / 4; k4++) {
        float4 v = xr[k4];
#pragma unroll
        for (int j = 0; j < HID; j++) {
            acc[j] += v.x * w[(k4 * 4 + 0) * HID + j]
                    + v.y * w[(k4 * 4 + 1) * HID + j]
                    + v.z * w[(k4 * 4 + 2) * HID + j]
                    + v.w * w[(k4 * 4 + 3) * HID + j];
        }
    }
    float di = dinv[n];
    float4* o = (float4*)(h1s + (size_t)n * HID);
    o[0] = make_float4(di * acc[0], di * acc[1], di * acc[2], di * acc[3]);
    o[1] = make_float4(di * acc[4], di * acc[5], di * acc[6], di * acc[7]);
    o[2] = make_float4(di * acc[8], di * acc[9], di * acc[10], di * acc[11]);
    o[3] = make_float4(di * acc[12], di * acc[13], di * acc[14], di * acc[15]);
}

// pull layer 1, fused bias+relu+@W2: one wave per node, lanes=[4 edges x 16 feats]
__global__ __launch_bounds__(256) void k_pull1(
    const int* __restrict__ rs, const int* __restrict__ re,
    const int* __restrict__ csr, const float* __restrict__ h1s,
    const float* __restrict__ dinv, const float* __restrict__ b1,
    const float* __restrict__ W2, float* __restrict__ h2s) {
    int n = blockIdx.x * 4 + (threadIdx.x >> 6);
    if (n >= N_NODES) return;
    int lane = threadIdx.x & 63;
    int es = lane >> 4, j = lane & 15;
    int beg = rs[n], end = re[n];
    float acc = 0.f;
    for (int i = beg + es; i < end; i += 4) {
        int s = csr[i];
        acc += h1s[(size_t)s * HID + j];
    }
    acc += __shfl_xor(acc, 16, 64);
    acc += __shfl_xor(acc, 32, 64);
    float di = dinv[n];
    float v = fmaxf(di * (acc + h1s[(size_t)n * HID + j]) + b1[j], 0.f);
    float p0 = v * W2[j * 2 + 0];
    float p1 = v * W2[j * 2 + 1];
#pragma unroll
    for (int m = 1; m <= 8; m <<= 1) {
        p0 += __shfl_xor(p0, m, 64);
        p1 += __shfl_xor(p1, m, 64);
    }
    if (lane == 0) *(float2*)(h2s + (size_t)n * 2) = make_float2(di * p0, di * p1);
}

// pull layer 2, fused log_softmax: one wave per node, lanes=[32 edges x 2 feats]
__global__ __launch_bounds__(256) void k_pull2(
    const int* __restrict__ rs, const int* __restrict__ re,
    const int* __restrict__ csr, const float* __restrict__ h2s,
    const float* __restrict__ dinv, const float* __restrict__ b2,
    float* __restrict__ out) {
    int n = blockIdx.x * 4 + (threadIdx.x >> 6);
    if (n >= N_NODES) return;
    int lane = threadIdx.x & 63;
    int e = lane >> 1, k = lane & 1;
    int beg = rs[n], end = re[n];
    float acc = 0.f;
    for (int i = beg + e; i < end; i += 32) {
        int s = csr[i];
        acc += h2s[(size_t)s * 2 + k];
    }
#pragma unroll
    for (int m = 2; m <= 32; m <<= 1) acc += __shfl_xor(acc, m, 64);
    float di = dinv[n];
    float o = di * (acc + h2s[(size_t)n * 2 + k]) + b2[k];
    float other = __shfl_xor(o, 1, 64);
    float mx = fmaxf(o, other);
    float lse = mx + logf(expf(o - mx) + expf(other - mx));
    if (lane < 2) out[(size_t)n * 2 + k] = o - lse;
}

extern "C" void kernel_launch(void* const* d_in, const int* in_sizes, int n_in,
                              void* d_out, int out_size, void* d_ws, size_t ws_size,
                              hipStream_t stream) {
    const float* x  = (const float*)d_in[0];
    const int*   ei = (const int*)d_in[1];
    const int*   srcv = ei;
    const int*   dstv = ei + N_EDGES;
    const float* W1 = (const float*)d_in[2];
    const float* b1 = (const float*)d_in[3];
    const float* W2 = (const float*)d_in[4];
    const float* b2 = (const float*)d_in[5];
    float* out = (float*)d_out;

    float* ws   = (float*)d_ws;
    int*   cnt  = (int*)(ws + OFF_CNT);      // becomes dinv (float) after scanC
    float* dinv = ws + OFF_CNT;
    int*   rs   = (int*)(ws + OFF_RS);
    int*   cur  = (int*)(ws + OFF_CUR);      // becomes row-end after fill
    int*   part = (int*)(ws + OFF_PART);
    float* h1s  = ws + OFF_H1;
    float* h2s  = ws + OFF_H2;
    int*   csr  = (int*)(ws + OFF_CSR);

    hipMemsetAsync(cnt, 0, (size_t)NPAD * sizeof(int), stream);

    k_degree<<<(N_EDGES + 255) / 256, 256, 0, stream>>>(dstv, cnt);
    k_scanA<<<NBLK, 256, 0, stream>>>(cnt, part);
    k_scanB<<<1, 128, 0, stream>>>(part);
    k_scanC<<<NBLK, 256, 0, stream>>>(cnt, part, rs, cur);
    int fill_grid = (N_EDGES / 4 + 255) / 256;
    for (int p = 0; p < NPASS; p++) {
        k_fillpass<<<fill_grid, 256, 0, stream>>>(srcv, dstv, cur, csr,
                                                  p * PASS_SZ, (p + 1) * PASS_SZ);
    }
    k_lin1s<<<(N_NODES + 255) / 256, 256, 0, stream>>>(x, W1, dinv, h1s);
    k_pull1<<<(N_NODES + 3) / 4, 256, 0, stream>>>(rs, cur, csr, h1s, dinv, b1, W2, h2s);
    k_pull2<<<(N_NODES + 3) / 4, 256, 0, stream>>>(rs, cur, csr, h2s, dinv, b2, out);
}

// Round 9
// 342.714 us; speedup vs baseline: 3.4443x; 1.5947x over previous
//
#include <hip/hip_runtime.h>
#include <math.h>
#include <stdint.h>

#define N_NODES 100000
#define N_EDGES 3200000
#define IN_DIM  64
#define HID     16
#define OUTD    2

#define NPAD    100352            // N padded to multiple of 1024
#define CHUNK   1024
#define NBLK    (NPAD / CHUNK)    // 98 scan blocks

#define NPASS   8
#define PASS_SZ (N_NODES / NPASS) // 12500

#define B_CHUNKS 128              // edge chunks
#define CHUNK_E  (N_EDGES / B_CHUNKS)  // 25000 edges per chunk
#define HALF     (NPAD / 2)       // 50176 nodes per histogram half
#define HWORDS   (HALF / 4)       // 12544 u32 words (uint8-packed), 50 KB LDS

// workspace layout (float offsets, then byte arrays) — ~37.3 MB total
#define OFF_CNT   0                          // int deg counts
#define OFF_RS    (OFF_CNT + NPAD)           // row starts (exclusive scan)
#define OFF_CUR   (OFF_RS + NPAD)            // row ENDS (written by scanC)
#define OFF_PART  (OFF_CUR + NPAD)           // scan partials
#define OFF_H1    (OFF_PART + 1024)          // h1s = dinv[n] * (x@W1)   [N,16]
#define OFF_H2    (OFF_H1 + N_NODES * HID)   // h2s = dinv[n] * h2_raw   [N,2]
#define OFF_CSR   (OFF_H2 + N_NODES * OUTD)  // CSR src ids (int)        [E]
#define WS_FLOATS (OFF_CSR + N_EDGES)
// byte arrays appended after the float region:
//   chunkcnt[B_CHUNKS][NPAD] uint8 (counts, then exclusive chunk-prefix in place)
//   rank[N_EDGES] uint8 (rank of edge within its (chunk, dst) group)

// --- CSR construction without global atomics ------------------------------
// Max in-degree of this random graph: mean 32, sigma 5.7 -> P(deg>75) ~ 2e-11.
// uint8 counts/prefix/rank are safe.

__global__ __launch_bounds__(256) void k_hist(const int* __restrict__ dst,
                                              uint8_t* __restrict__ rank,
                                              uint8_t* __restrict__ chunkcnt) {
    __shared__ unsigned int hist[HWORDS];
    int b = blockIdx.x >> 1, half = blockIdx.x & 1;
    for (int i = threadIdx.x; i < HWORDS; i += 256) hist[i] = 0u;
    __syncthreads();
    int base = b * CHUNK_E;
    int lo = half * HALF;
    for (int i = threadIdx.x; i < CHUNK_E; i += 256) {
        int e = base + i;
        int d = dst[e] - lo;
        if ((unsigned)d < (unsigned)HALF) {
            unsigned sh = (d & 3) * 8;
            unsigned old = atomicAdd(&hist[d >> 2], 1u << sh);
            rank[e] = (uint8_t)((old >> sh) & 0xFFu);   // rank within (chunk, d)
        }
    }
    __syncthreads();
    unsigned int* cc = (unsigned int*)(chunkcnt + (size_t)b * NPAD + lo);
    for (int i = threadIdx.x; i < HWORDS; i += 256) cc[i] = hist[i];
}

// per node: deg = sum over chunks; overwrite chunkcnt with exclusive prefix
__global__ void k_colscan(uint8_t* __restrict__ cc, int* __restrict__ cnt) {
    int n = blockIdx.x * 256 + threadIdx.x;   // grid covers NPAD exactly
    int acc = 0;
    for (int b = 0; b < B_CHUNKS; b++) {
        size_t idx = (size_t)b * NPAD + n;
        int c = cc[idx];
        cc[idx] = (uint8_t)acc;               // exclusive chunk-prefix (<= deg < 256)
        acc += c;
    }
    cnt[n] = acc;
}

// per-block sums of cnt (chunk=1024, 256 thr x int4)
__global__ void k_scanA(const int* __restrict__ cnt, int* __restrict__ part) {
    int t = threadIdx.x;
    int base = blockIdx.x * CHUNK + t * 4;
    int4 c = *(const int4*)(cnt + base);
    int s = c.x + c.y + c.z + c.w;
#pragma unroll
    for (int off = 32; off; off >>= 1) s += __shfl_down(s, off, 64);
    __shared__ int wsum[4];
    if ((t & 63) == 0) wsum[t >> 6] = s;
    __syncthreads();
    if (t == 0) part[blockIdx.x] = wsum[0] + wsum[1] + wsum[2] + wsum[3];
}

// exclusive scan of the NBLK partials, in place (1 block, 128 thr)
__global__ void k_scanB(int* __restrict__ part) {
    int i = threadIdx.x;
    int lane = i & 63;
    int v = (i < NBLK) ? part[i] : 0;
    int x = v;
#pragma unroll
    for (int off = 1; off < 64; off <<= 1) {
        int y = __shfl_up(x, off, 64);
        if (lane >= off) x += y;
    }
    __shared__ int w0;
    if (i == 63) w0 = x;
    __syncthreads();
    if (i >= 64) x += w0;
    if (i < NBLK) part[i] = x - v;   // exclusive
}

// write row starts + row ENDS; convert cnt -> dinv in place
__global__ void k_scanC(int* __restrict__ cnt_dinv, const int* __restrict__ part,
                        int* __restrict__ rs, int* __restrict__ re) {
    int t = threadIdx.x;
    int lane = t & 63, wid = t >> 6;
    int base = blockIdx.x * CHUNK + t * 4;
    int4 c = *(const int4*)(cnt_dinv + base);
    int s0 = c.x, s1 = s0 + c.y, s2 = s1 + c.z, tot = s2 + c.w;
    int x = tot;
#pragma unroll
    for (int off = 1; off < 64; off <<= 1) {
        int y = __shfl_up(x, off, 64);
        if (lane >= off) x += y;
    }
    int texcl = x - tot;
    __shared__ int wtot[4];
    if (lane == 63) wtot[wid] = x;
    __syncthreads();
    int wbase = 0;
#pragma unroll
    for (int w = 0; w < 4; w++) if (w < wid) wbase += wtot[w];
    int b = part[blockIdx.x] + wbase + texcl;
    *(int4*)(rs + base) = make_int4(b, b + s0, b + s1, b + s2);
    *(int4*)(re + base) = make_int4(b + s0, b + s1, b + s2, b + tot);  // row ends
    float4 dv = make_float4(rsqrtf((float)(c.x + 1)), rsqrtf((float)(c.y + 1)),
                            rsqrtf((float)(c.z + 1)), rsqrtf((float)(c.w + 1)));
    *(float4*)((float*)cnt_dinv + base) = dv;
}

// atomic-free fill: pos = rs[d] + prefix[chunk][d] + rank[e]  (a bijection).
// dst-range partitioning keeps csr stores L2-local (write-amp fix from r6).
__global__ __launch_bounds__(256) void k_fillp(
    const int* __restrict__ src, const int* __restrict__ dst,
    const int* __restrict__ rs, const uint8_t* __restrict__ prefix,
    const uint8_t* __restrict__ rank, int* __restrict__ csr) {
    int b = blockIdx.x >> 3, r = blockIdx.x & 7;
    int lo = r * PASS_SZ, hi = lo + PASS_SZ;
    int base = b * CHUNK_E;
    const uint8_t* pb = prefix + (size_t)b * NPAD;
    for (int i = threadIdx.x; i < CHUNK_E; i += 256) {
        int e = base + i;
        int d = dst[e];
        if (d >= lo && d < hi) {
            int pos = rs[d] + (int)pb[d] + (int)rank[e];
            csr[pos] = src[e];
        }
    }
}

// h1s[n] = dinv[n] * (x[n] @ W1)
__global__ void k_lin1s(const float* __restrict__ x, const float* __restrict__ W1,
                        const float* __restrict__ dinv, float* __restrict__ h1s) {
    __shared__ float w[IN_DIM * HID];
    for (int i = threadIdx.x; i < IN_DIM * HID; i += blockDim.x) w[i] = W1[i];
    __syncthreads();
    int n = blockIdx.x * blockDim.x + threadIdx.x;
    if (n >= N_NODES) return;
    float acc[HID];
#pragma unroll
    for (int j = 0; j < HID; j++) acc[j] = 0.f;
    const float4* xr = (const float4*)(x + (size_t)n * IN_DIM);
#pragma unroll
    for (int k4 = 0; k4 < IN_DIM / 4; k4++) {
        float4 v = xr[k4];
#pragma unroll
        for (int j = 0; j < HID; j++) {
            acc[j] += v.x * w[(k4 * 4 + 0) * HID + j]
                    + v.y * w[(k4 * 4 + 1) * HID + j]
                    + v.z * w[(k4 * 4 + 2) * HID + j]
                    + v.w * w[(k4 * 4 + 3) * HID + j];
        }
    }
    float di = dinv[n];
    float4* o = (float4*)(h1s + (size_t)n * HID);
    o[0] = make_float4(di * acc[0], di * acc[1], di * acc[2], di * acc[3]);
    o[1] = make_float4(di * acc[4], di * acc[5], di * acc[6], di * acc[7]);
    o[2] = make_float4(di * acc[8], di * acc[9], di * acc[10], di * acc[11]);
    o[3] = make_float4(di * acc[12], di * acc[13], di * acc[14], di * acc[15]);
}

// pull layer 1, fused bias+relu+@W2: one wave per node, lanes=[4 edges x 16 feats]
__global__ __launch_bounds__(256) void k_pull1(
    const int* __restrict__ rs, const int* __restrict__ re,
    const int* __restrict__ csr, const float* __restrict__ h1s,
    const float* __restrict__ dinv, const float* __restrict__ b1,
    const float* __restrict__ W2, float* __restrict__ h2s) {
    int n = blockIdx.x * 4 + (threadIdx.x >> 6);
    if (n >= N_NODES) return;
    int lane = threadIdx.x & 63;
    int es = lane >> 4, j = lane & 15;
    int beg = rs[n], end = re[n];
    float acc = 0.f;
    for (int i = beg + es; i < end; i += 4) {
        int s = csr[i];
        acc += h1s[(size_t)s * HID + j];
    }
    acc += __shfl_xor(acc, 16, 64);
    acc += __shfl_xor(acc, 32, 64);
    float di = dinv[n];
    float v = fmaxf(di * (acc + h1s[(size_t)n * HID + j]) + b1[j], 0.f);
    float p0 = v * W2[j * 2 + 0];
    float p1 = v * W2[j * 2 + 1];
#pragma unroll
    for (int m = 1; m <= 8; m <<= 1) {
        p0 += __shfl_xor(p0, m, 64);
        p1 += __shfl_xor(p1, m, 64);
    }
    if (lane == 0) *(float2*)(h2s + (size_t)n * 2) = make_float2(di * p0, di * p1);
}

// pull layer 2, fused log_softmax: one wave per node, lanes=[32 edges x 2 feats]
__global__ __launch_bounds__(256) void k_pull2(
    const int* __restrict__ rs, const int* __restrict__ re,
    const int* __restrict__ csr, const float* __restrict__ h2s,
    const float* __restrict__ dinv, const float* __restrict__ b2,
    float* __restrict__ out) {
    int n = blockIdx.x * 4 + (threadIdx.x >> 6);
    if (n >= N_NODES) return;
    int lane = threadIdx.x & 63;
    int e = lane >> 1, k = lane & 1;
    int beg = rs[n], end = re[n];
    float acc = 0.f;
    for (int i = beg + e; i < end; i += 32) {
        int s = csr[i];
        acc += h2s[(size_t)s * 2 + k];
    }
#pragma unroll
    for (int m = 2; m <= 32; m <<= 1) acc += __shfl_xor(acc, m, 64);
    float di = dinv[n];
    float o = di * (acc + h2s[(size_t)n * 2 + k]) + b2[k];
    float other = __shfl_xor(o, 1, 64);
    float mx = fmaxf(o, other);
    float lse = mx + logf(expf(o - mx) + expf(other - mx));
    if (lane < 2) out[(size_t)n * 2 + k] = o - lse;
}

extern "C" void kernel_launch(void* const* d_in, const int* in_sizes, int n_in,
                              void* d_out, int out_size, void* d_ws, size_t ws_size,
                              hipStream_t stream) {
    const float* x  = (const float*)d_in[0];
    const int*   ei = (const int*)d_in[1];
    const int*   srcv = ei;
    const int*   dstv = ei + N_EDGES;
    const float* W1 = (const float*)d_in[2];
    const float* b1 = (const float*)d_in[3];
    const float* W2 = (const float*)d_in[4];
    const float* b2 = (const float*)d_in[5];
    float* out = (float*)d_out;

    float*   ws   = (float*)d_ws;
    int*     cnt  = (int*)(ws + OFF_CNT);    // becomes dinv (float) after scanC
    float*   dinv = ws + OFF_CNT;
    int*     rs   = (int*)(ws + OFF_RS);
    int*     re   = (int*)(ws + OFF_CUR);    // row ends
    int*     part = (int*)(ws + OFF_PART);
    float*   h1s  = ws + OFF_H1;
    float*   h2s  = ws + OFF_H2;
    int*     csr  = (int*)(ws + OFF_CSR);
    uint8_t* chunkcnt = (uint8_t*)(ws + WS_FLOATS);                       // [B][NPAD]
    uint8_t* rank     = chunkcnt + (size_t)B_CHUNKS * NPAD;               // [E]

    k_hist<<<B_CHUNKS * 2, 256, 0, stream>>>(dstv, rank, chunkcnt);
    k_colscan<<<NPAD / 256, 256, 0, stream>>>(chunkcnt, cnt);
    k_scanA<<<NBLK, 256, 0, stream>>>(cnt, part);
    k_scanB<<<1, 128, 0, stream>>>(part);
    k_scanC<<<NBLK, 256, 0, stream>>>(cnt, part, rs, re);
    k_fillp<<<B_CHUNKS * 8, 256, 0, stream>>>(srcv, dstv, rs, chunkcnt, rank, csr);
    k_lin1s<<<(N_NODES + 255) / 256, 256, 0, stream>>>(x, W1, dinv, h1s);
    k_pull1<<<(N_NODES + 3) / 4, 256, 0, stream>>>(rs, re, csr, h1s, dinv, b1, W2, h2s);
    k_pull2<<<(N_NODES + 3) / 4, 256, 0, stream>>>(rs, re, csr, h2s, dinv, b2, out);
}

// Round 10
// 328.968 us; speedup vs baseline: 3.5882x; 1.0418x over previous
//
#include <hip/hip_runtime.h>
#include <math.h>
#include <stdint.h>

#define N_NODES 100000
#define N_EDGES 3200000
#define IN_DIM  64
#define HID     16
#define OUTD    2

#define NPAD    100352                 // N padded (multiple of 1024)
#define B_CHUNKS 128                   // edge chunks
#define CHUNK_E  (N_EDGES / B_CHUNKS)  // 25000 edges per chunk
#define NB       256                   // dst buckets
#define BK_NODES (NPAD / NB)           // 392 nodes per bucket
#define BK_CAP   14336                 // mean 12500 + 16 sigma, LDS cap

// workspace layout (float offsets) — ~46.9 MB
#define OFF_DINV  0
#define OFF_RS    (OFF_DINV + NPAD)
#define OFF_RE    (OFF_RS + NPAD)
#define OFF_H1    (OFF_RE + NPAD)            // h1s = dinv[n]*(x@W1) [N,16]
#define OFF_H2    (OFF_H1 + N_NODES * HID)   // h2s = dinv[n]*h2raw  [N,2]
#define OFF_CSR   (OFF_H2 + N_NODES * OUTD)  // CSR src ids [E]
#define OFF_PAIRS (OFF_CSR + N_EDGES)        // u64 (src<<32|dst) [E] (8B-aligned: even)
#define OFF_HCNT  (OFF_PAIRS + 2 * N_EDGES)  // u32 [B_CHUNKS][NB]
#define OFF_BST   (OFF_HCNT + B_CHUNKS * NB) // int [NB+1]

// ---- CSR build: zero global atomics, ~1x write amplification --------------

__global__ __launch_bounds__(256) void k_bhist(const int* __restrict__ dst,
                                               unsigned* __restrict__ hcnt) {
    __shared__ unsigned h[NB];
    h[threadIdx.x] = 0u;
    __syncthreads();
    int base = blockIdx.x * CHUNK_E;
    for (int i = threadIdx.x; i < CHUNK_E; i += 256)
        atomicAdd(&h[dst[base + i] / BK_NODES], 1u);
    __syncthreads();
    hcnt[blockIdx.x * NB + threadIdx.x] = h[threadIdx.x];
}

// bucket starts + in-place chunk-prefix: hcnt[b][bk] -> absolute run base
__global__ __launch_bounds__(256) void k_bscan(unsigned* __restrict__ hcnt,
                                               int* __restrict__ bstart) {
    int bk = threadIdx.x, lane = bk & 63, wid = bk >> 6;
    int tot = 0;
    for (int b = 0; b < B_CHUNKS; b++) tot += (int)hcnt[(size_t)b * NB + bk];
    int x = tot;
#pragma unroll
    for (int off = 1; off < 64; off <<= 1) {
        int y = __shfl_up(x, off, 64);
        if (lane >= off) x += y;
    }
    __shared__ int wt[4];
    if (lane == 63) wt[wid] = x;
    __syncthreads();
    int wb = 0;
#pragma unroll
    for (int w = 0; w < 4; w++) if (w < wid) wb += wt[w];
    int start = wb + x - tot;
    bstart[bk] = start;
    if (bk == NB - 1) bstart[NB] = start + tot;
    unsigned run = (unsigned)start;
    for (int b = 0; b < B_CHUNKS; b++) {
        unsigned c = hcnt[(size_t)b * NB + bk];
        hcnt[(size_t)b * NB + bk] = run;
        run += c;
    }
}

// scatter edges into bucket-grouped pairs; per-(chunk,bucket) runs are
// contiguous (~780 B) so stores cover full lines -> no write amplification
__global__ __launch_bounds__(256) void k_bscatter(
    const int* __restrict__ src, const int* __restrict__ dst,
    const unsigned* __restrict__ hcnt, unsigned long long* __restrict__ pairs) {
    __shared__ unsigned cur[NB];
    cur[threadIdx.x] = hcnt[(size_t)blockIdx.x * NB + threadIdx.x];
    __syncthreads();
    int base = blockIdx.x * CHUNK_E;
    for (int i = threadIdx.x; i < CHUNK_E; i += 256) {
        int e = base + i;
        int d = dst[e];
        unsigned pos = atomicAdd(&cur[d / BK_NODES], 1u);
        pairs[pos] = ((unsigned long long)(unsigned)src[e] << 32) | (unsigned)d;
    }
}

// one block per bucket: LDS counting-sort by dst, coalesced csr write,
// and emit rs/re/dinv for the bucket's 392 nodes (replaces all int scans)
__global__ __launch_bounds__(256) void k_bsort(
    const unsigned long long* __restrict__ pairs, const int* __restrict__ bstart,
    int* __restrict__ csr, int* __restrict__ rs, int* __restrict__ re,
    float* __restrict__ dinv) {
    __shared__ unsigned long long lp[BK_CAP];
    __shared__ unsigned cnt[BK_NODES];
    __shared__ unsigned rstart[BK_NODES];
    int bk = blockIdx.x;
    int s0 = bstart[bk], s1 = bstart[bk + 1];
    int ne = s1 - s0;
    if (ne > BK_CAP) ne = BK_CAP;            // statistically impossible guard
    for (int i = threadIdx.x; i < ne; i += 256) lp[i] = pairs[s0 + i];
    for (int i = threadIdx.x; i < BK_NODES; i += 256) cnt[i] = 0u;
    __syncthreads();
    int nlo = bk * BK_NODES;
    for (int i = threadIdx.x; i < ne; i += 256) {
        int dl = (int)(unsigned)(lp[i] & 0xffffffffu) - nlo;
        atomicAdd(&cnt[dl], 1u);
    }
    __syncthreads();
    // exclusive scan of cnt[392] on wave 0 (7 elems/lane)
    if (threadIdx.x < 64) {
        int lane = threadIdx.x;
        unsigned loc[7];
        unsigned s = 0;
#pragma unroll
        for (int q = 0; q < 7; q++) {
            int idx = lane * 7 + q;
            unsigned c = (idx < BK_NODES) ? cnt[idx] : 0u;
            loc[q] = s; s += c;
        }
        unsigned x = s;
#pragma unroll
        for (int off = 1; off < 64; off <<= 1) {
            unsigned y = __shfl_up((int)x, off, 64);
            if (lane >= off) x += y;
        }
        unsigned basev = x - s;
#pragma unroll
        for (int q = 0; q < 7; q++) {
            int idx = lane * 7 + q;
            if (idx < BK_NODES) rstart[idx] = basev + loc[q];
        }
    }
    __syncthreads();
    for (int i = threadIdx.x; i < BK_NODES; i += 256) {
        int n = nlo + i;
        unsigned st = rstart[i], en = st + cnt[i];
        rs[n] = s0 + (int)st;
        re[n] = s0 + (int)en;
        dinv[n] = rsqrtf((float)(cnt[i] + 1));
    }
    __syncthreads();
    for (int i = threadIdx.x; i < ne; i += 256) {
        unsigned long long p = lp[i];
        int dl = (int)(unsigned)(p & 0xffffffffu) - nlo;
        unsigned pos = atomicAdd(&rstart[dl], 1u);
        csr[s0 + (int)pos] = (int)(unsigned)(p >> 32);
    }
}

// ---- dense + pull phases (unchanged from round 9) -------------------------

__global__ void k_lin1s(const float* __restrict__ x, const float* __restrict__ W1,
                        const float* __restrict__ dinv, float* __restrict__ h1s) {
    __shared__ float w[IN_DIM * HID];
    for (int i = threadIdx.x; i < IN_DIM * HID; i += blockDim.x) w[i] = W1[i];
    __syncthreads();
    int n = blockIdx.x * blockDim.x + threadIdx.x;
    if (n >= N_NODES) return;
    float acc[HID];
#pragma unroll
    for (int j = 0; j < HID; j++) acc[j] = 0.f;
    const float4* xr = (const float4*)(x + (size_t)n * IN_DIM);
#pragma unroll
    for (int k4 = 0; k4 < IN_DIM / 4; k4++) {
        float4 v = xr[k4];
#pragma unroll
        for (int j = 0; j < HID; j++) {
            acc[j] += v.x * w[(k4 * 4 + 0) * HID + j]
                    + v.y * w[(k4 * 4 + 1) * HID + j]
                    + v.z * w[(k4 * 4 + 2) * HID + j]
                    + v.w * w[(k4 * 4 + 3) * HID + j];
        }
    }
    float di = dinv[n];
    float4* o = (float4*)(h1s + (size_t)n * HID);
    o[0] = make_float4(di * acc[0], di * acc[1], di * acc[2], di * acc[3]);
    o[1] = make_float4(di * acc[4], di * acc[5], di * acc[6], di * acc[7]);
    o[2] = make_float4(di * acc[8], di * acc[9], di * acc[10], di * acc[11]);
    o[3] = make_float4(di * acc[12], di * acc[13], di * acc[14], di * acc[15]);
}

__global__ __launch_bounds__(256) void k_pull1(
    const int* __restrict__ rs, const int* __restrict__ re,
    const int* __restrict__ csr, const float* __restrict__ h1s,
    const float* __restrict__ dinv, const float* __restrict__ b1,
    const float* __restrict__ W2, float* __restrict__ h2s) {
    int n = blockIdx.x * 4 + (threadIdx.x >> 6);
    if (n >= N_NODES) return;
    int lane = threadIdx.x & 63;
    int es = lane >> 4, j = lane & 15;
    int beg = rs[n], end = re[n];
    float acc = 0.f;
    for (int i = beg + es; i < end; i += 4) {
        int s = csr[i];
        acc += h1s[(size_t)s * HID + j];
    }
    acc += __shfl_xor(acc, 16, 64);
    acc += __shfl_xor(acc, 32, 64);
    float di = dinv[n];
    float v = fmaxf(di * (acc + h1s[(size_t)n * HID + j]) + b1[j], 0.f);
    float p0 = v * W2[j * 2 + 0];
    float p1 = v * W2[j * 2 + 1];
#pragma unroll
    for (int m = 1; m <= 8; m <<= 1) {
        p0 += __shfl_xor(p0, m, 64);
        p1 += __shfl_xor(p1, m, 64);
    }
    if (lane == 0) *(float2*)(h2s + (size_t)n * 2) = make_float2(di * p0, di * p1);
}

__global__ __launch_bounds__(256) void k_pull2(
    const int* __restrict__ rs, const int* __restrict__ re,
    const int* __restrict__ csr, const float* __restrict__ h2s,
    const float* __restrict__ dinv, const float* __restrict__ b2,
    float* __restrict__ out) {
    int n = blockIdx.x * 4 + (threadIdx.x >> 6);
    if (n >= N_NODES) return;
    int lane = threadIdx.x & 63;
    int e = lane >> 1, k = lane & 1;
    int beg = rs[n], end = re[n];
    float acc = 0.f;
    for (int i = beg + e; i < end; i += 32) {
        int s = csr[i];
        acc += h2s[(size_t)s * 2 + k];
    }
#pragma unroll
    for (int m = 2; m <= 32; m <<= 1) acc += __shfl_xor(acc, m, 64);
    float di = dinv[n];
    float o = di * (acc + h2s[(size_t)n * 2 + k]) + b2[k];
    float other = __shfl_xor(o, 1, 64);
    float mx = fmaxf(o, other);
    float lse = mx + logf(expf(o - mx) + expf(other - mx));
    if (lane < 2) out[(size_t)n * 2 + k] = o - lse;
}

extern "C" void kernel_launch(void* const* d_in, const int* in_sizes, int n_in,
                              void* d_out, int out_size, void* d_ws, size_t ws_size,
                              hipStream_t stream) {
    const float* x  = (const float*)d_in[0];
    const int*   ei = (const int*)d_in[1];
    const int*   srcv = ei;
    const int*   dstv = ei + N_EDGES;
    const float* W1 = (const float*)d_in[2];
    const float* b1 = (const float*)d_in[3];
    const float* W2 = (const float*)d_in[4];
    const float* b2 = (const float*)d_in[5];
    float* out = (float*)d_out;

    float*              ws     = (float*)d_ws;
    float*              dinv   = ws + OFF_DINV;
    int*                rs     = (int*)(ws + OFF_RS);
    int*                re     = (int*)(ws + OFF_RE);
    float*              h1s    = ws + OFF_H1;
    float*              h2s    = ws + OFF_H2;
    int*                csr    = (int*)(ws + OFF_CSR);
    unsigned long long* pairs  = (unsigned long long*)(ws + OFF_PAIRS);
    unsigned*           hcnt   = (unsigned*)(ws + OFF_HCNT);
    int*                bstart = (int*)(ws + OFF_BST);

    k_bhist<<<B_CHUNKS, 256, 0, stream>>>(dstv, hcnt);
    k_bscan<<<1, 256, 0, stream>>>(hcnt, bstart);
    k_bscatter<<<B_CHUNKS, 256, 0, stream>>>(srcv, dstv, hcnt, pairs);
    k_bsort<<<NB, 256, 0, stream>>>(pairs, bstart, csr, rs, re, dinv);
    k_lin1s<<<(N_NODES + 255) / 256, 256, 0, stream>>>(x, W1, dinv, h1s);
    k_pull1<<<(N_NODES + 3) / 4, 256, 0, stream>>>(rs, re, csr, h1s, dinv, b1, W2, h2s);
    k_pull2<<<(N_NODES + 3) / 4, 256, 0, stream>>>(rs, re, csr, h2s, dinv, b2, out);
}